// Round 1
// baseline (36.895 us; speedup 1.0000x reference)
//
#include <hip/hip_runtime.h>
#include <math.h>

#define K_TOP 16
#define D_DIM 1024

// One block per (s, r) row: q = s*64 + r, q in [0, 2048).
// Wave 0: top-16 selection. All waves: one-hot write (16 x 1024 floats).
__global__ __launch_bounds__(256) void dps_topk_kernel(
    const float* __restrict__ logits,  // (64, 1024)
    const float* __restrict__ gn,      // (32, 64, 1024)
    float* __restrict__ out)           // (32, 64, 16, 1024)
{
    const int q    = blockIdx.x;
    const int r    = q & 63;
    const int tid  = threadIdx.x;
    const int lane = tid & 63;
    const int wave = tid >> 6;

    __shared__ int sel_lds[K_TOP];

    if (wave == 0) {
        // Lane l owns elements d = l + 64*j, j = 0..15 (coalesced loads).
        float v[16];
        const float* lrow = logits + (size_t)r * D_DIM;
        const float* grow = gn + (size_t)q * D_DIM;
        #pragma unroll
        for (int j = 0; j < 16; ++j) {
            const int d = lane + 64 * j;
            v[j] = lrow[d] + grow[d];
        }

        unsigned chosen = 0;   // bitmask of already-selected j's (this lane)
        int my_sel = 0;        // lane k ends up holding round-k winner index

        for (int round = 0; round < K_TOP; ++round) {
            // Per-lane argmax over the 16 register elements, fully unrolled
            // (static indices only — runtime-indexed arrays spill to scratch).
            float bv = -INFINITY;
            int   bi = 0x7fffffff;
            #pragma unroll
            for (int j = 0; j < 16; ++j) {
                if (!(chosen & (1u << j))) {
                    // strict > keeps smaller j (= smaller global index) on tie
                    if (v[j] > bv) { bv = v[j]; bi = lane + 64 * j; }
                }
            }
            // 64-lane butterfly argmax; tie-break: prefer smaller index
            #pragma unroll
            for (int off = 32; off > 0; off >>= 1) {
                const float ov = __shfl_xor(bv, off);
                const int   oi = __shfl_xor(bi, off);
                if (ov > bv || (ov == bv && oi < bi)) { bv = ov; bi = oi; }
            }
            // Owner invalidates its element via the mask (no runtime v[] index).
            if (lane == (bi & 63)) chosen |= 1u << (bi >> 6);
            if (lane == round)     my_sel = bi;
        }

        // Lanes 0..15 hold the 16 winners (value-descending order, arbitrary
        // index order). Rank = #indices smaller than mine -> ascending sort.
        int rank = 0;
        #pragma unroll
        for (int j = 0; j < K_TOP; ++j) {
            const int other = __shfl(my_sel, j);
            rank += (other < my_sel) ? 1 : 0;
        }
        if (lane < K_TOP) sel_lds[rank] = my_sel;
    }
    __syncthreads();

    // Write the 16 x 1024 one-hot block: 256 threads x 4 floats per k-row.
    float* orow = out + (size_t)q * (K_TOP * D_DIM);
    const int d0 = tid * 4;
    #pragma unroll
    for (int k = 0; k < K_TOP; ++k) {
        const int s = sel_lds[k];
        float4 val;
        val.x = (d0 + 0 == s) ? 1.0f : 0.0f;
        val.y = (d0 + 1 == s) ? 1.0f : 0.0f;
        val.z = (d0 + 2 == s) ? 1.0f : 0.0f;
        val.w = (d0 + 3 == s) ? 1.0f : 0.0f;
        *reinterpret_cast<float4*>(orow + (size_t)k * D_DIM + d0) = val;
    }
}

extern "C" void kernel_launch(void* const* d_in, const int* in_sizes, int n_in,
                              void* d_out, int out_size, void* d_ws, size_t ws_size,
                              hipStream_t stream) {
    const float* logits = (const float*)d_in[0];  // (64, 1024) f32
    const float* gn     = (const float*)d_in[1];  // (32, 64, 1024) f32
    float* out          = (float*)d_out;          // (32, 64, 16, 1024) f32

    dps_topk_kernel<<<dim3(2048), dim3(256), 0, stream>>>(logits, gn, out);
}